// Round 8
// baseline (4937.909 us; speedup 1.0000x reference)
//
#include <hip/hip_runtime.h>
#include <math.h>

#define NB 131072
#define LS 133                       // LDS row stride in floats (133%32=5 -> max 2-way bank aliasing, free)
#define SCALE_LOSS (1.0f/(2.0f*131072.0f*128.0f))

// d_ws float offsets (pre-transposed weights, [k][c] layout, c contiguous)
#define OFF_WT1 0                    // We1^T [256][128]
#define OFF_WT2 32768                // We2^T [128][128]
#define OFF_WT3 49152
#define OFF_WT4 65536
#define OFF_D1A 81920                // Wd1[:, :128]^T
#define OFF_D1B 98304                // Wd1[:, 128:]^T
#define OFF_WD2 114688
#define OFF_WD3 131072
#define OFF_MCB 147456               // mean of codebook over K, [128]
#define OFF_SC2 147584               // np-pairwise sum(cb[j]^2), [9]
#define WSF_F32 147593

__global__ void prep_kernel(const float* __restrict__ We1, const float* __restrict__ We2,
                            const float* __restrict__ We3, const float* __restrict__ We4,
                            const float* __restrict__ Wd1, const float* __restrict__ Wd2,
                            const float* __restrict__ Wd3, const float* __restrict__ cb,
                            float* __restrict__ ws)
{
    int t = blockIdx.x * 256 + threadIdx.x;
    if (t >= WSF_F32) return;
    if (t < OFF_WT2)      { int u = t - OFF_WT1; int k = u >> 7, c = u & 127; ws[t] = We1[c*256 + k]; }
    else if (t < OFF_WT3) { int u = t - OFF_WT2; int k = u >> 7, c = u & 127; ws[t] = We2[c*128 + k]; }
    else if (t < OFF_WT4) { int u = t - OFF_WT3; int k = u >> 7, c = u & 127; ws[t] = We3[c*128 + k]; }
    else if (t < OFF_D1A) { int u = t - OFF_WT4; int k = u >> 7, c = u & 127; ws[t] = We4[c*128 + k]; }
    else if (t < OFF_D1B) { int u = t - OFF_D1A; int k = u >> 7, c = u & 127; ws[t] = Wd1[c*256 + k]; }
    else if (t < OFF_WD2) { int u = t - OFF_D1B; int k = u >> 7, c = u & 127; ws[t] = Wd1[c*256 + 128 + k]; }
    else if (t < OFF_WD3) { int u = t - OFF_WD2; int k = u >> 7, c = u & 127; ws[t] = Wd2[c*128 + k]; }
    else if (t < OFF_MCB) { int u = t - OFF_WD3; int k = u >> 7, c = u & 127; ws[t] = Wd3[c*128 + k]; }
    else if (t < OFF_SC2) {
        int e = t - OFF_MCB;        // mean over K (loss only, loose threshold)
        float s = 0.f;
        for (int j = 0; j < 9; ++j) s += cb[j*128 + e];
        ws[t] = s / 9.0f;
    } else {
        // np.sum(cb[j]**2) with numpy pairwise-8 algorithm (n=128), contraction-blocked
        int j = t - OFF_SC2;
        const float* __restrict__ row = cb + j*128;
        float r[8];
        #pragma unroll
        for (int q = 0; q < 8; ++q) r[q] = __fmul_rn(row[q], row[q]);
        for (int i = 8; i < 128; i += 8) {
            #pragma unroll
            for (int q = 0; q < 8; ++q) r[q] = __fadd_rn(r[q], __fmul_rn(row[i+q], row[i+q]));
        }
        ws[t] = __fadd_rn(__fadd_rn(__fadd_rn(r[0], r[1]), __fadd_rn(r[2], r[3])),
                          __fadd_rn(__fadd_rn(r[4], r[5]), __fadd_rn(r[6], r[7])));
    }
}

// acc[c] += sum_k hrow[k] * wt[k*128+c] — ascending-k single-accumulator FMA (BLAS order)
__device__ __forceinline__ void gemv_accum(const float* __restrict__ wt, const float* hrow, float* acc)
{
    for (int k = 0; k < 128; ++k) {
        float hk = hrow[k];
        const float* __restrict__ w = wt + k*128;
        #pragma unroll
        for (int c = 0; c < 128; ++c)
            acc[c] = __fmaf_rn(hk, w[c], acc[c]);
    }
}

__device__ __forceinline__ float lrelu(float v) {
    // exact np form: where(v >= 0, v, 0.01*v); mul kept un-fused
    return v >= 0.f ? v : __fmul_rn(0.01f, v);
}

__device__ __forceinline__ void act_store(const float* acc, const float* __restrict__ bias, float* hrow)
{
    #pragma unroll
    for (int c = 0; c < 128; ++c)
        hrow[c] = lrelu(__fadd_rn(acc[c], bias[c]));
}

// cooperatively stage 64 rows x 128 cols of x (one K-half) into hbuf
__device__ __forceinline__ void stage_tile(const float* __restrict__ x, int row0, int half,
                                           int lane, float* hbuf)
{
    __syncthreads();                       // everyone done reading previous contents
    int rb = lane >> 5;
    int c4 = (lane & 31) * 4;
    for (int it = 0; it < 32; ++it) {
        int row = it*2 + rb;
        float4 v = *reinterpret_cast<const float4*>(&x[(size_t)(row0 + row)*256 + half*128 + c4]);
        float* d = &hbuf[row*LS + c4];
        d[0] = v.x; d[1] = v.y; d[2] = v.z; d[3] = v.w;
    }
    __syncthreads();
}

__device__ __forceinline__ void encode_stream(const float* __restrict__ x, int row0, int lane,
                                              float* hbuf, float* hrow, const float* __restrict__ ws,
                                              const float* __restrict__ be1, const float* __restrict__ be2,
                                              const float* __restrict__ be3, const float* __restrict__ be4)
{
    float acc[128];
    #pragma unroll
    for (int c = 0; c < 128; ++c) acc[c] = 0.f;
    stage_tile(x, row0, 0, lane, hbuf);
    gemv_accum(ws + OFF_WT1, hrow, acc);
    stage_tile(x, row0, 1, lane, hbuf);
    gemv_accum(ws + OFF_WT1 + 128*128, hrow, acc);
    act_store(acc, be1, hrow);

    #pragma unroll
    for (int c = 0; c < 128; ++c) acc[c] = 0.f;
    gemv_accum(ws + OFF_WT2, hrow, acc);
    act_store(acc, be2, hrow);

    #pragma unroll
    for (int c = 0; c < 128; ++c) acc[c] = 0.f;
    gemv_accum(ws + OFF_WT3, hrow, acc);
    act_store(acc, be3, hrow);

    #pragma unroll
    for (int c = 0; c < 128; ++c) acc[c] = 0.f;
    gemv_accum(ws + OFF_WT4, hrow, acc);
    #pragma unroll
    for (int c = 0; c < 128; ++c) hrow[c] = __fadd_rn(acc[c], be4[c]);   // z_e (no activation)
}

// np-mimicry VQ: d = (pairwise8(z^2) + sc2[j]) - 2*fma_dot(z, c_j); argmin first-min
__device__ __forceinline__ void vq_eval_np(const float* hrow, const float* cbs,
                                           const float* __restrict__ sc2, const float* mcb,
                                           int& idx, float& lvq, float& lm)
{
    // sz: numpy pairwise-8 over z*z (n=128), no contraction
    float r[8];
    #pragma unroll
    for (int q = 0; q < 8; ++q) r[q] = __fmul_rn(hrow[q], hrow[q]);
    for (int i = 8; i < 128; i += 8) {
        #pragma unroll
        for (int q = 0; q < 8; ++q) r[q] = __fadd_rn(r[q], __fmul_rn(hrow[i+q], hrow[i+q]));
    }
    float sz = __fadd_rn(__fadd_rn(__fadd_rn(r[0], r[1]), __fadd_rn(r[2], r[3])),
                         __fadd_rn(__fadd_rn(r[4], r[5]), __fadd_rn(r[6], r[7])));

    // dot_j: ascending-k single-accumulator FMA (BLAS sgemm micro-kernel order)
    float dot[9];
    #pragma unroll
    for (int j = 0; j < 9; ++j) dot[j] = 0.f;
    for (int k = 0; k < 128; ++k) {
        float z = hrow[k];
        #pragma unroll
        for (int j = 0; j < 9; ++j) dot[j] = __fmaf_rn(z, cbs[j*LS + k], dot[j]);
    }

    float dist[9];
    #pragma unroll
    for (int j = 0; j < 9; ++j)
        dist[j] = __fsub_rn(__fadd_rn(sz, sc2[j]), __fmul_rn(2.0f, dot[j]));

    int bi = 0; float bd = dist[0];
    #pragma unroll
    for (int j = 1; j < 9; ++j) { if (dist[j] < bd) { bd = dist[j]; bi = j; } }  // first-min = np.argmin
    idx = bi;

    // losses (loose thresholds): direct sums
    float lv = 0.f, lmm = 0.f;
    for (int k = 0; k < 128; ++k) {
        float z = hrow[k];
        float dc = z - cbs[bi*LS + k]; lv = fmaf(dc, dc, lv);
        float dm = z - mcb[k];         lmm = fmaf(dm, dm, lmm);
    }
    lvq = lv; lm = lmm;
}

__device__ __forceinline__ float decoder_eval(int ia, int ib, const float* cbs, float* hrow,
                                              const float* __restrict__ ws,
                                              const float* __restrict__ bd1, const float* __restrict__ bd2,
                                              const float* __restrict__ bd3, const float* __restrict__ Wd4,
                                              const float* __restrict__ bd4)
{
    float acc[128];
    #pragma unroll
    for (int c = 0; c < 128; ++c) acc[c] = 0.f;
    gemv_accum(ws + OFF_D1A, &cbs[ia*LS], acc);
    gemv_accum(ws + OFF_D1B, &cbs[ib*LS], acc);
    act_store(acc, bd1, hrow);

    #pragma unroll
    for (int c = 0; c < 128; ++c) acc[c] = 0.f;
    gemv_accum(ws + OFF_WD2, hrow, acc);
    act_store(acc, bd2, hrow);

    #pragma unroll
    for (int c = 0; c < 128; ++c) acc[c] = 0.f;
    gemv_accum(ws + OFF_WD3, hrow, acc);
    act_store(acc, bd3, hrow);

    float o = bd4[0];
    for (int c = 0; c < 128; ++c) o = fmaf(hrow[c], Wd4[c], o);
    return tanhf(o);
}

__global__ __launch_bounds__(64, 1) void vqnet_kernel(
    const float* __restrict__ xA, const float* __restrict__ xB,
    const float* __restrict__ be1, const float* __restrict__ be2,
    const float* __restrict__ be3, const float* __restrict__ be4,
    const float* __restrict__ cb,
    const float* __restrict__ bd1, const float* __restrict__ bd2,
    const float* __restrict__ bd3, const float* __restrict__ Wd4,
    const float* __restrict__ bd4,
    const float* __restrict__ ws, float* __restrict__ out)
{
    __shared__ float hbuf[64*LS];   // per-lane activation row
    __shared__ float cbs[9*LS];     // staged codebook
    const int lane = threadIdx.x;
    const int row0 = blockIdx.x * 64;
    const int pair = row0 + lane;

    for (int t = lane; t < 9*128; t += 64) { int j = t >> 7, e = t & 127; cbs[j*LS + e] = cb[t]; }
    // visibility via the __syncthreads inside the first stage_tile

    float* hrow = &hbuf[lane*LS];
    const float* mcb = ws + OFF_MCB;
    const float* sc2 = ws + OFF_SC2;

    encode_stream(xA, row0, lane, hbuf, hrow, ws, be1, be2, be3, be4);
    int idxA; float lvqA, lmA;
    vq_eval_np(hrow, cbs, sc2, mcb, idxA, lvqA, lmA);

    encode_stream(xB, row0, lane, hbuf, hrow, ws, be1, be2, be3, be4);
    int idxB; float lvqB, lmB;
    vq_eval_np(hrow, cbs, sc2, mcb, idxB, lvqB, lmB);

    float o1 = decoder_eval(idxA, idxB, cbs, hrow, ws, bd1, bd2, bd3, Wd4, bd4);
    float o2 = decoder_eval(idxB, idxA, cbs, hrow, ws, bd1, bd2, bd3, Wd4, bd4);

    out[pair]            = 0.5f * (o1 - o2);
    out[NB + 2 + pair]   = (float)idxA;
    out[2*NB + 2 + pair] = (float)idxB;

    float lvq = lvqA + lvqB, lm = lmA + lmB;
    #pragma unroll
    for (int off = 32; off; off >>= 1) {
        lvq += __shfl_down(lvq, off, 64);
        lm  += __shfl_down(lm,  off, 64);
    }
    if (lane == 0) {
        atomicAdd(&out[NB],     lvq * SCALE_LOSS);
        atomicAdd(&out[NB + 1], lm  * SCALE_LOSS);
    }
}

extern "C" void kernel_launch(void* const* d_in, const int* in_sizes, int n_in,
                              void* d_out, int out_size, void* d_ws, size_t ws_size,
                              hipStream_t stream)
{
    const float* xA  = (const float*)d_in[0];
    const float* xB  = (const float*)d_in[1];
    const float* We1 = (const float*)d_in[2];
    const float* be1 = (const float*)d_in[3];
    const float* We2 = (const float*)d_in[4];
    const float* be2 = (const float*)d_in[5];
    const float* We3 = (const float*)d_in[6];
    const float* be3 = (const float*)d_in[7];
    const float* We4 = (const float*)d_in[8];
    const float* be4 = (const float*)d_in[9];
    const float* cb  = (const float*)d_in[10];
    const float* Wd1 = (const float*)d_in[11];
    const float* bd1 = (const float*)d_in[12];
    const float* Wd2 = (const float*)d_in[13];
    const float* bd2 = (const float*)d_in[14];
    const float* Wd3 = (const float*)d_in[15];
    const float* bd3 = (const float*)d_in[16];
    const float* Wd4 = (const float*)d_in[17];
    const float* bd4 = (const float*)d_in[18];
    float* out = (float*)d_out;
    float* ws  = (float*)d_ws;

    // zero the two scalar-loss accumulators (d_out is poisoned 0xAA before every launch)
    hipMemsetAsync((char*)d_out + (size_t)NB * sizeof(float), 0, 2 * sizeof(float), stream);

    prep_kernel<<<(WSF_F32 + 255) / 256, 256, 0, stream>>>(We1, We2, We3, We4, Wd1, Wd2, Wd3, cb, ws);
    vqnet_kernel<<<NB / 64, 64, 0, stream>>>(xA, xB, be1, be2, be3, be4, cb,
                                             bd1, bd2, bd3, Wd4, bd4, ws, out);
}